// Round 2
// baseline (1982.626 us; speedup 1.0000x reference)
//
#include <hip/hip_runtime.h>
#include <hip/hip_bf16.h>

#define M_ROWS 17664   // B*T = 64*276
#define K_CODES 8192
#define D_DIM 256
#define N_ELEM 4521984 // M_ROWS * 256

typedef unsigned short ushort_t;
typedef __attribute__((ext_vector_type(8))) short short8v;  // 8 bf16 (4 VGPRs)
typedef __attribute__((ext_vector_type(4))) float f32x4;

__device__ __forceinline__ unsigned long long umin64(unsigned long long a, unsigned long long b) { return a < b ? a : b; }
__device__ __forceinline__ unsigned long long umax64(unsigned long long a, unsigned long long b) { return a > b ? a : b; }

__device__ __forceinline__ unsigned long long shflxor64(unsigned long long v, int m) {
    unsigned lo = (unsigned)v, hi = (unsigned)(v >> 32);
    lo = __shfl_xor(lo, m);
    hi = __shfl_xor(hi, m);
    return ((unsigned long long)hi << 32) | lo;
}
__device__ __forceinline__ unsigned long long shfl64(unsigned long long v, int src) {
    unsigned lo = (unsigned)v, hi = (unsigned)(v >> 32);
    lo = __shfl(lo, src);
    hi = __shfl(hi, src);
    return ((unsigned long long)hi << 32) | lo;
}

__device__ __forceinline__ void gload16(const void* g, void* l) {
    __builtin_amdgcn_global_load_lds((const __attribute__((address_space(1))) void*)g,
                                     (__attribute__((address_space(3))) void*)l, 16, 0, 0);
}

// ---------------------------------------------------------------------------
// Exact replication of numpy pairwise sum of squares for a 256-wide row.
// ---------------------------------------------------------------------------
__global__ void rowsq_kernel(const float* __restrict__ X,
                             float* __restrict__ out, int rows) {
    int r = blockIdx.x * blockDim.x + threadIdx.x;
    if (r >= rows) return;
    const float* p = X + (size_t)r * D_DIM;
    float half_sum[2];
#pragma unroll
    for (int h = 0; h < 2; ++h) {
        const float* q = p + h * 128;
        float acc[8];
#pragma unroll
        for (int j = 0; j < 8; ++j) acc[j] = __fmul_rn(q[j], q[j]);
        for (int i = 8; i < 128; i += 8) {
#pragma unroll
            for (int j = 0; j < 8; ++j)
                acc[j] = __fadd_rn(acc[j], __fmul_rn(q[i + j], q[i + j]));
        }
        float s01 = __fadd_rn(acc[0], acc[1]);
        float s23 = __fadd_rn(acc[2], acc[3]);
        float s45 = __fadd_rn(acc[4], acc[5]);
        float s67 = __fadd_rn(acc[6], acc[7]);
        half_sum[h] = __fadd_rn(__fadd_rn(s01, s23), __fadd_rn(s45, s67));
    }
    out[r] = __fadd_rn(half_sum[0], half_sum[1]);
}

__global__ void init_kernel(unsigned long long* __restrict__ packed,
                            float* __restrict__ loss_acc) {
    int i = blockIdx.x * blockDim.x + threadIdx.x;
    if (i < M_ROWS) packed[i] = 0xFFFFFFFFFFFFFFFFull;
    if (i == 0) loss_acc[0] = 0.0f;
}

__global__ void init_loss_kernel(float* __restrict__ loss_acc) {
    if (threadIdx.x == 0 && blockIdx.x == 0) loss_acc[0] = 0.0f;
}

// ---------------------------------------------------------------------------
// Split fp32 -> (hi, lo) bf16 pair. Out layout [row][512]: cols 0-255 = hi,
// 256-511 = lo. One thread per 4 elements.
// ---------------------------------------------------------------------------
__global__ void split_kernel(const float* __restrict__ X,
                             ushort_t* __restrict__ Xs, int rows) {
    int idx = blockIdx.x * blockDim.x + threadIdx.x;
    int total = rows * 64;
    if (idx >= total) return;
    int row = idx >> 6;
    int c4 = (idx & 63) * 4;
    float4 v = *(const float4*)(X + (size_t)row * D_DIM + c4);
    ushort_t h[4], l[4];
    float vv[4] = {v.x, v.y, v.z, v.w};
#pragma unroll
    for (int j = 0; j < 4; ++j) {
        __hip_bfloat16 b1 = __float2bfloat16(vv[j]);
        float bf = __bfloat162float(b1);
        float r = __fsub_rn(vv[j], bf);
        __hip_bfloat16 b2 = __float2bfloat16(r);
        h[j] = *reinterpret_cast<ushort_t*>(&b1);
        l[j] = *reinterpret_cast<ushort_t*>(&b2);
    }
    *(ushort4*)(Xs + (size_t)row * 512 + c4) = make_ushort4(h[0], h[1], h[2], h[3]);
    *(ushort4*)(Xs + (size_t)row * 512 + 256 + c4) = make_ushort4(l[0], l[1], l[2], l[3]);
}

// ---------------------------------------------------------------------------
// Phase 1: bf16 MFMA GEMM (Keff=768: z1c1 + z1c2 + z2c1), 128x128 tile,
// 4 waves (each 64x64), global_load_lds staging, top-2 candidate packing
// per (row, 64-col wave group) -> blockcand[M][128][2] u64.
// ---------------------------------------------------------------------------
__global__ __launch_bounds__(256) void phase1_kernel(
    const ushort_t* __restrict__ Zs,   // [M][512] bf16 bits
    const ushort_t* __restrict__ Cs,   // [K][512] bf16 bits
    const float* __restrict__ asum, const float* __restrict__ bsum,
    unsigned long long* __restrict__ blockcand) {
    __shared__ ushort_t As[128 * 32];  // 8 KiB
    __shared__ ushort_t Bs[128 * 32];  // 8 KiB

    const int t = threadIdx.x;
    const int wid = t >> 6, lane = t & 63;
    const int bm = blockIdx.x / 64, bn = blockIdx.x % 64;  // 138 x 64
    const int m0 = bm * 128, n0 = bn * 128;
    const int wm = wid >> 1, wn = wid & 1;

    f32x4 acc[4][4];
#pragma unroll
    for (int i = 0; i < 4; ++i)
#pragma unroll
        for (int j = 0; j < 4; ++j) acc[i][j] = (f32x4){0.f, 0.f, 0.f, 0.f};

    // staging geometry: wave wid, issue j covers rows (wid*2+j)*16 .. +16
    const int srow = (lane >> 2);          // 0..15 within chunk
    const int scol = (lane & 3) * 8;       // bf16 units within 32-col tile row

    const int segA[3] = {0, 0, 256};
    const int segB[3] = {0, 256, 0};

#pragma unroll 1
    for (int seg = 0; seg < 3; ++seg) {
        const ushort_t* Ab = Zs + (size_t)m0 * 512 + segA[seg];
        const ushort_t* Bb = Cs + (size_t)n0 * 512 + segB[seg];
#pragma unroll 1
        for (int k0 = 0; k0 < 256; k0 += 32) {
            // stage A (2 issues) + B (2 issues) per wave
            {
                int r0 = (wid * 2 + 0) * 16 + srow;
                int r1 = (wid * 2 + 1) * 16 + srow;
                gload16(Ab + (size_t)r0 * 512 + k0 + scol, As + (wid * 2 + 0) * 512);
                gload16(Ab + (size_t)r1 * 512 + k0 + scol, As + (wid * 2 + 1) * 512);
                gload16(Bb + (size_t)r0 * 512 + k0 + scol, Bs + (wid * 2 + 0) * 512);
                gload16(Bb + (size_t)r1 * 512 + k0 + scol, Bs + (wid * 2 + 1) * 512);
            }
            __syncthreads();
            const ushort_t* Aw = As + (wm * 64) * 32;
            const ushort_t* Bw = Bs + (wn * 64) * 32;
            short8v a[4], b[4];
#pragma unroll
            for (int mi = 0; mi < 4; ++mi)
                a[mi] = *(const short8v*)(Aw + (size_t)(mi * 16 + (lane & 15)) * 32 + (lane >> 4) * 8);
#pragma unroll
            for (int ni = 0; ni < 4; ++ni)
                b[ni] = *(const short8v*)(Bw + (size_t)(ni * 16 + (lane & 15)) * 32 + (lane >> 4) * 8);
#pragma unroll
            for (int mi = 0; mi < 4; ++mi)
#pragma unroll
                for (int ni = 0; ni < 4; ++ni)
                    acc[mi][ni] = __builtin_amdgcn_mfma_f32_16x16x32_bf16(
                        a[mi], b[ni], acc[mi][ni], 0, 0, 0);
            __syncthreads();
        }
    }

    // epilogue: per-row top-2 over this wave's 64 cols
    unsigned long long* cand = (unsigned long long*)As;  // [128][2 wn][2] = 4 KiB
#pragma unroll 1
    for (int mi = 0; mi < 4; ++mi) {
#pragma unroll 1
        for (int r = 0; r < 4; ++r) {
            int lrow = wm * 64 + mi * 16 + (lane >> 4) * 4 + r;
            float ar = asum[m0 + lrow];
            unsigned long long b1 = 0xFFFFFFFFFFFFFFFFull, b2 = 0xFFFFFFFFFFFFFFFFull;
#pragma unroll
            for (int ni = 0; ni < 4; ++ni) {
                int lcol = wn * 64 + ni * 16 + (lane & 15);
                float bc = bsum[n0 + lcol];
                float dt = (ar + bc) - 2.0f * acc[mi][ni][r];
                unsigned long long p =
                    ((unsigned long long)__float_as_uint(dt) << 32) | (unsigned)(n0 + lcol);
                if (p < b1) { b2 = b1; b1 = p; }
                else if (p < b2) { b2 = p; }
            }
#pragma unroll
            for (int s = 1; s < 16; s <<= 1) {
                unsigned long long o1 = shflxor64(b1, s);
                unsigned long long o2 = shflxor64(b2, s);
                unsigned long long n1 = umin64(b1, o1);
                unsigned long long n2 = umin64(umax64(b1, o1), umin64(b2, o2));
                b1 = n1; b2 = n2;
            }
            if ((lane & 15) == 0) {
                cand[(size_t)lrow * 4 + wn * 2 + 0] = b1;
                cand[(size_t)lrow * 4 + wn * 2 + 1] = b2;
            }
        }
    }
    __syncthreads();
    // coalesced write: blockcand[row][group=bn*2+wn][2]
    {
        int row = t >> 1, pair = t & 1;
        unsigned long long v0 = cand[(size_t)row * 4 + pair * 2 + 0];
        unsigned long long v1 = cand[(size_t)row * 4 + pair * 2 + 1];
        unsigned long long* dst =
            blockcand + (size_t)(m0 + row) * 256 + (size_t)bn * 4 + pair * 2;
        dst[0] = v0; dst[1] = v1;
    }
}

// ---------------------------------------------------------------------------
// Phase 2 + finalize: per row (one wave), threshold-scan 256 candidates,
// exact fp32 quantized distance per survivor (np-structured), index tiebreak,
// then z_q_st / min_idx / loss exactly as round-1.
// ---------------------------------------------------------------------------
__global__ __launch_bounds__(256) void phase2_kernel(
    const float* __restrict__ Z, const float* __restrict__ CB,
    const float* __restrict__ asum, const float* __restrict__ bsum,
    const unsigned long long* __restrict__ blockcand,
    float* __restrict__ out, float* __restrict__ loss_acc) {
    float* out_zq = out + 2;
    float* out_idx = out + 2 + (size_t)N_ELEM;
    const int lane = threadIdx.x & 63;
    const int w = threadIdx.x >> 6;
    const int row = blockIdx.x * 4 + w;
    float lsum = 0.0f;

    if (row < M_ROWS) {
        const unsigned long long* cr = blockcand + (size_t)row * 256;
        unsigned long long e0 = cr[lane], e1 = cr[lane + 64];
        unsigned long long e2 = cr[lane + 128], e3 = cr[lane + 192];
        unsigned long long mn = umin64(umin64(e0, e1), umin64(e2, e3));
#pragma unroll
        for (int s = 1; s < 64; s <<= 1) mn = umin64(mn, shflxor64(mn, s));
        float dmin = __uint_as_float((unsigned)(mn >> 32));
        float thr = dmin + 8.0e-5f;
        unsigned long long m0m = __ballot(__uint_as_float((unsigned)(e0 >> 32)) <= thr);
        unsigned long long m1m = __ballot(__uint_as_float((unsigned)(e1 >> 32)) <= thr);
        unsigned long long m2m = __ballot(__uint_as_float((unsigned)(e2 >> 32)) <= thr);
        unsigned long long m3m = __ballot(__uint_as_float((unsigned)(e3 >> 32)) <= thr);

        const float4 zv = *(const float4*)(Z + (size_t)row * D_DIM + lane * 4);
        float ar = asum[row];
        unsigned long long best = 0xFFFFFFFFFFFFFFFFull;

        while (m0m | m1m | m2m | m3m) {
            unsigned long long e;
            if (m0m)      { int b = __ffsll((unsigned long long)m0m) - 1; m0m &= m0m - 1; e = shfl64(e0, b); }
            else if (m1m) { int b = __ffsll((unsigned long long)m1m) - 1; m1m &= m1m - 1; e = shfl64(e1, b); }
            else if (m2m) { int b = __ffsll((unsigned long long)m2m) - 1; m2m &= m2m - 1; e = shfl64(e2, b); }
            else          { int b = __ffsll((unsigned long long)m3m) - 1; m3m &= m3m - 1; e = shfl64(e3, b); }
            unsigned col = (unsigned)e;
            const float4 cv = *(const float4*)(CB + (size_t)col * D_DIM + lane * 4);
            float s = __fmul_rn(zv.x, cv.x);
            s = __builtin_fmaf(zv.y, cv.y, s);
            s = __builtin_fmaf(zv.z, cv.z, s);
            s = __builtin_fmaf(zv.w, cv.w, s);
#pragma unroll
            for (int m = 1; m < 64; m <<= 1) s += __shfl_xor(s, m);
            float d = __fsub_rn(__fadd_rn(ar, bsum[col]), __fmul_rn(2.0f, s));
            unsigned long long p = ((unsigned long long)__float_as_uint(d) << 32) | col;
            best = umin64(best, p);
        }

        unsigned wincol = (unsigned)best;
        if (lane == 0) out_idx[row] = (float)wincol;
        const float4 cv = *(const float4*)(CB + (size_t)wincol * D_DIM + lane * 4);
        float d0 = __fsub_rn(cv.x, zv.x);
        float d1 = __fsub_rn(cv.y, zv.y);
        float d2 = __fsub_rn(cv.z, zv.z);
        float d3 = __fsub_rn(cv.w, zv.w);
        float2 o0 = make_float2(__fadd_rn(zv.x, d0), __fadd_rn(zv.y, d1));
        float2 o1 = make_float2(__fadd_rn(zv.z, d2), __fadd_rn(zv.w, d3));
        *(float2*)(out_zq + (size_t)row * D_DIM + lane * 4) = o0;
        *(float2*)(out_zq + (size_t)row * D_DIM + lane * 4 + 2) = o1;
        lsum = d0 * d0 + d1 * d1 + d2 * d2 + d3 * d3;
    }
#pragma unroll
    for (int m = 1; m < 64; m <<= 1) lsum += __shfl_xor(lsum, m);
    __shared__ float red[4];
    if (lane == 0) red[w] = lsum;
    __syncthreads();
    if (threadIdx.x == 0) {
        float s = ((red[0] + red[1]) + (red[2] + red[3]));
        atomicAdd(loss_acc, s);
    }
}

__global__ void write_losses(const float* __restrict__ loss_acc,
                             float* __restrict__ out) {
    float l = __fdiv_rn(loss_acc[0], (float)N_ELEM);
    out[0] = l;
    out[1] = l;
}

// ======================= round-1 fallback (fp32 VALU) =======================
#define BM 128
#define BN 128
#define BK 32
#define LDT 132

__global__ __launch_bounds__(256) void gemm_argmin_kernel(
    const float* __restrict__ Z, const float* __restrict__ CB,
    const float* __restrict__ asum, const float* __restrict__ bsum,
    unsigned long long* __restrict__ packed) {
    __shared__ float As[BK][LDT];
    __shared__ float Bs[BK][LDT];
    const int bid = blockIdx.x;
    const int bm = bid >> 6, bn = bid & 63;
    const int m0 = bm * BM, n0 = bn * BN;
    const int t = threadIdx.x;
    const int ty = t >> 4, tx = t & 15;
    float acc[8][8];
#pragma unroll
    for (int i = 0; i < 8; ++i)
#pragma unroll
        for (int j = 0; j < 8; ++j) acc[i][j] = 0.0f;
    for (int k0 = 0; k0 < D_DIM; k0 += BK) {
#pragma unroll
        for (int i = 0; i < 4; ++i) {
            int idx = t + i * 256;
            int row = idx >> 3, kq = idx & 7;
            const float4 av = *(const float4*)(Z + (size_t)(m0 + row) * D_DIM + k0 + kq * 4);
            As[kq * 4 + 0][row] = av.x; As[kq * 4 + 1][row] = av.y;
            As[kq * 4 + 2][row] = av.z; As[kq * 4 + 3][row] = av.w;
            const float4 bv = *(const float4*)(CB + (size_t)(n0 + row) * D_DIM + k0 + kq * 4);
            Bs[kq * 4 + 0][row] = bv.x; Bs[kq * 4 + 1][row] = bv.y;
            Bs[kq * 4 + 2][row] = bv.z; Bs[kq * 4 + 3][row] = bv.w;
        }
        __syncthreads();
#pragma unroll
        for (int k = 0; k < BK; ++k) {
            float af[8], bf[8];
            *(float4*)(af)     = *(const float4*)(&As[k][ty * 4]);
            *(float4*)(af + 4) = *(const float4*)(&As[k][64 + ty * 4]);
            *(float4*)(bf)     = *(const float4*)(&Bs[k][tx * 4]);
            *(float4*)(bf + 4) = *(const float4*)(&Bs[k][64 + tx * 4]);
#pragma unroll
            for (int i = 0; i < 8; ++i)
#pragma unroll
                for (int j = 0; j < 8; ++j)
                    acc[i][j] = __builtin_fmaf(af[i], bf[j], acc[i][j]);
        }
        __syncthreads();
    }
    float ar[8], bc[8];
    int rowIdx[8], colIdx[8];
#pragma unroll
    for (int i = 0; i < 8; ++i) {
        rowIdx[i] = (i < 4) ? (4 * ty + i) : (64 + 4 * ty + (i - 4));
        ar[i] = asum[m0 + rowIdx[i]];
    }
#pragma unroll
    for (int j = 0; j < 8; ++j) {
        colIdx[j] = (j < 4) ? (4 * tx + j) : (64 + 4 * tx + (j - 4));
        bc[j] = bsum[n0 + colIdx[j]];
    }
#pragma unroll
    for (int i = 0; i < 8; ++i) {
        unsigned long long best = 0xFFFFFFFFFFFFFFFFull;
#pragma unroll
        for (int j = 0; j < 8; ++j) {
            float ts = __fadd_rn(ar[i], bc[j]);
            float d = __fsub_rn(ts, __fmul_rn(2.0f, acc[i][j]));
            unsigned long long p = ((unsigned long long)__float_as_uint(d) << 32) |
                                   (unsigned)(n0 + colIdx[j]);
            best = (p < best) ? p : best;
        }
#pragma unroll
        for (int m = 1; m <= 8; m <<= 1) {
            unsigned long long o = shflxor64(best, m);
            best = (o < best) ? o : best;
        }
        if (tx == 0) atomicMin(&packed[m0 + rowIdx[i]], best);
    }
}

__global__ __launch_bounds__(256) void finalize_kernel(
    const float* __restrict__ Z, const float* __restrict__ CB,
    const unsigned long long* __restrict__ packed,
    float* __restrict__ out, float* __restrict__ loss_acc) {
    float* out_zq = out + 2;
    float* out_idx = out + 2 + (size_t)N_ELEM;
    const int lane = threadIdx.x & 63;
    const int wid = (blockIdx.x * blockDim.x + threadIdx.x) >> 6;
    const int nw = (gridDim.x * blockDim.x) >> 6;
    float lsum = 0.0f;
    for (int row = wid; row < M_ROWS; row += nw) {
        unsigned long long pk = packed[row];
        unsigned idx = (unsigned)(pk & 0xFFFFFFFFull);
        if (lane == 0) out_idx[row] = (float)idx;
        const float4 zv = *(const float4*)(Z + (size_t)row * D_DIM + lane * 4);
        const float4 cv = *(const float4*)(CB + (size_t)idx * D_DIM + lane * 4);
        float d0 = __fsub_rn(cv.x, zv.x);
        float d1 = __fsub_rn(cv.y, zv.y);
        float d2 = __fsub_rn(cv.z, zv.z);
        float d3 = __fsub_rn(cv.w, zv.w);
        float2 o0 = make_float2(__fadd_rn(zv.x, d0), __fadd_rn(zv.y, d1));
        float2 o1 = make_float2(__fadd_rn(zv.z, d2), __fadd_rn(zv.w, d3));
        *(float2*)(out_zq + (size_t)row * D_DIM + lane * 4) = o0;
        *(float2*)(out_zq + (size_t)row * D_DIM + lane * 4 + 2) = o1;
        lsum += d0 * d0 + d1 * d1 + d2 * d2 + d3 * d3;
    }
#pragma unroll
    for (int m = 1; m < 64; m <<= 1) lsum += __shfl_xor(lsum, m);
    __shared__ float red[4];
    if (lane == 0) red[threadIdx.x >> 6] = lsum;
    __syncthreads();
    if (threadIdx.x == 0) {
        float s = ((red[0] + red[1]) + (red[2] + red[3]));
        atomicAdd(loss_acc, s);
    }
}

// ===========================================================================
extern "C" void kernel_launch(void* const* d_in, const int* in_sizes, int n_in,
                              void* d_out, int out_size, void* d_ws, size_t ws_size,
                              hipStream_t stream) {
    const float* Z = (const float*)d_in[0];    // [17664, 256]
    const float* CB = (const float*)d_in[1];   // [8192, 256]
    float* out = (float*)d_out;
    char* ws = (char*)d_ws;

    // new-path workspace layout
    const size_t offZs   = 0;
    const size_t offCs   = offZs + (size_t)M_ROWS * 512 * 2;      // 18,087,936
    const size_t offCand = offCs + (size_t)K_CODES * 512 * 2;     // + 8,388,608
    const size_t offAsum = offCand + (size_t)M_ROWS * 256 * 8;    // +36,175,872
    const size_t offBsum = offAsum + (size_t)M_ROWS * 4;
    const size_t offLoss = offBsum + (size_t)K_CODES * 4;
    const size_t need    = offLoss + 64;

    if (ws_size >= need) {
        ushort_t* Zs = (ushort_t*)(ws + offZs);
        ushort_t* Cs = (ushort_t*)(ws + offCs);
        unsigned long long* blockcand = (unsigned long long*)(ws + offCand);
        float* asum = (float*)(ws + offAsum);
        float* bsum = (float*)(ws + offBsum);
        float* loss_acc = (float*)(ws + offLoss);

        hipLaunchKernelGGL(init_loss_kernel, dim3(1), dim3(64), 0, stream, loss_acc);
        hipLaunchKernelGGL(rowsq_kernel, dim3((M_ROWS + 255) / 256), dim3(256), 0, stream,
                           Z, asum, M_ROWS);
        hipLaunchKernelGGL(rowsq_kernel, dim3((K_CODES + 255) / 256), dim3(256), 0, stream,
                           CB, bsum, K_CODES);
        hipLaunchKernelGGL(split_kernel, dim3((M_ROWS * 64 + 255) / 256), dim3(256), 0, stream,
                           Z, Zs, M_ROWS);
        hipLaunchKernelGGL(split_kernel, dim3((K_CODES * 64 + 255) / 256), dim3(256), 0, stream,
                           CB, Cs, K_CODES);
        hipLaunchKernelGGL(phase1_kernel, dim3((M_ROWS / 128) * (K_CODES / 128)),
                           dim3(256), 0, stream, Zs, Cs, asum, bsum, blockcand);
        hipLaunchKernelGGL(phase2_kernel, dim3(M_ROWS / 4), dim3(256), 0, stream,
                           Z, CB, asum, bsum, blockcand, out, loss_acc);
        hipLaunchKernelGGL(write_losses, dim3(1), dim3(1), 0, stream, loss_acc, out);
    } else {
        // round-1 fallback path
        float* asum = (float*)ws;
        float* bsum = (float*)(ws + (size_t)M_ROWS * 4);
        unsigned long long* packed =
            (unsigned long long*)(ws + (size_t)M_ROWS * 4 + (size_t)K_CODES * 4);
        float* loss_acc =
            (float*)(ws + (size_t)M_ROWS * 4 + (size_t)K_CODES * 4 + (size_t)M_ROWS * 8);

        hipLaunchKernelGGL(init_kernel, dim3((M_ROWS + 255) / 256), dim3(256), 0, stream,
                           packed, loss_acc);
        hipLaunchKernelGGL(rowsq_kernel, dim3((M_ROWS + 255) / 256), dim3(256), 0, stream,
                           Z, asum, M_ROWS);
        hipLaunchKernelGGL(rowsq_kernel, dim3((K_CODES + 255) / 256), dim3(256), 0, stream,
                           CB, bsum, K_CODES);
        hipLaunchKernelGGL(gemm_argmin_kernel, dim3((M_ROWS / BM) * (K_CODES / BN)),
                           dim3(256), 0, stream, Z, CB, asum, bsum, packed);
        hipLaunchKernelGGL(finalize_kernel, dim3(512), dim3(256), 0, stream,
                           Z, CB, packed, out, loss_acc);
        hipLaunchKernelGGL(write_losses, dim3(1), dim3(1), 0, stream, loss_acc, out);
    }
}

// Round 3
// 436.775 us; speedup vs baseline: 4.5392x; 4.5392x over previous
//
#include <hip/hip_runtime.h>
#include <hip/hip_bf16.h>

#define M_ROWS 17664   // B*T = 64*276
#define K_CODES 8192
#define D_DIM 256
#define N_ELEM 4521984 // M_ROWS * 256

typedef unsigned short ushort_t;
typedef __attribute__((ext_vector_type(8))) short short8v;  // 8 bf16 (4 VGPRs)
typedef __attribute__((ext_vector_type(4))) float f32x4;

__device__ __forceinline__ unsigned long long umin64(unsigned long long a, unsigned long long b) { return a < b ? a : b; }
__device__ __forceinline__ unsigned long long umax64(unsigned long long a, unsigned long long b) { return a > b ? a : b; }

__device__ __forceinline__ unsigned long long shflxor64(unsigned long long v, int m) {
    unsigned lo = (unsigned)v, hi = (unsigned)(v >> 32);
    lo = __shfl_xor(lo, m);
    hi = __shfl_xor(hi, m);
    return ((unsigned long long)hi << 32) | lo;
}
__device__ __forceinline__ unsigned long long shfl64(unsigned long long v, int src) {
    unsigned lo = (unsigned)v, hi = (unsigned)(v >> 32);
    lo = __shfl(lo, src);
    hi = __shfl(hi, src);
    return ((unsigned long long)hi << 32) | lo;
}

__device__ __forceinline__ void gload16(const void* g, void* l) {
    __builtin_amdgcn_global_load_lds((const __attribute__((address_space(1))) void*)g,
                                     (__attribute__((address_space(3))) void*)l, 16, 0, 0);
}

// ---------------------------------------------------------------------------
// Exact replication of numpy pairwise sum of squares for a 256-wide row.
// ---------------------------------------------------------------------------
__global__ void rowsq_kernel(const float* __restrict__ X,
                             float* __restrict__ out, int rows) {
    int r = blockIdx.x * blockDim.x + threadIdx.x;
    if (r >= rows) return;
    const float* p = X + (size_t)r * D_DIM;
    float half_sum[2];
#pragma unroll
    for (int h = 0; h < 2; ++h) {
        const float* q = p + h * 128;
        float acc[8];
#pragma unroll
        for (int j = 0; j < 8; ++j) acc[j] = __fmul_rn(q[j], q[j]);
        for (int i = 8; i < 128; i += 8) {
#pragma unroll
            for (int j = 0; j < 8; ++j)
                acc[j] = __fadd_rn(acc[j], __fmul_rn(q[i + j], q[i + j]));
        }
        float s01 = __fadd_rn(acc[0], acc[1]);
        float s23 = __fadd_rn(acc[2], acc[3]);
        float s45 = __fadd_rn(acc[4], acc[5]);
        float s67 = __fadd_rn(acc[6], acc[7]);
        half_sum[h] = __fadd_rn(__fadd_rn(s01, s23), __fadd_rn(s45, s67));
    }
    out[r] = __fadd_rn(half_sum[0], half_sum[1]);
}

__global__ void init_kernel(unsigned long long* __restrict__ packed,
                            float* __restrict__ loss_acc) {
    int i = blockIdx.x * blockDim.x + threadIdx.x;
    if (i < M_ROWS) packed[i] = 0xFFFFFFFFFFFFFFFFull;
    if (i == 0) loss_acc[0] = 0.0f;
}

__global__ void init_loss_kernel(float* __restrict__ loss_acc) {
    if (threadIdx.x == 0 && blockIdx.x == 0) loss_acc[0] = 0.0f;
}

// ---------------------------------------------------------------------------
// Split fp32 -> (hi, lo) bf16 pair. Out layout [row][512]: cols 0-255 = hi,
// 256-511 = lo.
// ---------------------------------------------------------------------------
__global__ void split_kernel(const float* __restrict__ X,
                             ushort_t* __restrict__ Xs, int rows) {
    int idx = blockIdx.x * blockDim.x + threadIdx.x;
    int total = rows * 64;
    if (idx >= total) return;
    int row = idx >> 6;
    int c4 = (idx & 63) * 4;
    float4 v = *(const float4*)(X + (size_t)row * D_DIM + c4);
    ushort_t h[4], l[4];
    float vv[4] = {v.x, v.y, v.z, v.w};
#pragma unroll
    for (int j = 0; j < 4; ++j) {
        __hip_bfloat16 b1 = __float2bfloat16(vv[j]);
        float bf = __bfloat162float(b1);
        float r = __fsub_rn(vv[j], bf);
        __hip_bfloat16 b2 = __float2bfloat16(r);
        h[j] = *reinterpret_cast<ushort_t*>(&b1);
        l[j] = *reinterpret_cast<ushort_t*>(&b2);
    }
    *(ushort4*)(Xs + (size_t)row * 512 + c4) = make_ushort4(h[0], h[1], h[2], h[3]);
    *(ushort4*)(Xs + (size_t)row * 512 + 256 + c4) = make_ushort4(l[0], l[1], l[2], l[3]);
}

// ---------------------------------------------------------------------------
// Phase 1: bf16 MFMA GEMM (Keff=768: z1c1 + z1c2 + z2c1), 128x128 tile,
// 4 waves (each 64x64), global_load_lds staging, top-2 candidate packing
// per (row, 64-col wave group) -> blockcand[M][256] u64.
// NOTE: every acc[][] access is compile-time-indexed (rule #20) -- the
// round-2 version runtime-indexed the epilogue and spilled acc to scratch
// (12.5 GB of HBM writes).
// ---------------------------------------------------------------------------
__global__ __launch_bounds__(256) void phase1_kernel(
    const ushort_t* __restrict__ Zs,   // [M][512] bf16 bits
    const ushort_t* __restrict__ Cs,   // [K][512] bf16 bits
    const float* __restrict__ asum, const float* __restrict__ bsum,
    unsigned long long* __restrict__ blockcand) {
    __shared__ ushort_t As[128 * 32];  // 8 KiB
    __shared__ ushort_t Bs[128 * 32];  // 8 KiB

    const int t = threadIdx.x;
    const int wid = t >> 6, lane = t & 63;
    const int bm = blockIdx.x / 64, bn = blockIdx.x % 64;  // 138 x 64
    const int m0 = bm * 128, n0 = bn * 128;
    const int wm = wid >> 1, wn = wid & 1;

    f32x4 acc[4][4];
#pragma unroll
    for (int i = 0; i < 4; ++i)
#pragma unroll
        for (int j = 0; j < 4; ++j) acc[i][j] = (f32x4){0.f, 0.f, 0.f, 0.f};

    const int srow = (lane >> 2);          // 0..15 within 16-row chunk
    const int scol = (lane & 3) * 8;       // bf16 units within 32-col tile row

#pragma unroll 1
    for (int seg = 0; seg < 3; ++seg) {
        const int sa = (seg == 2) ? 256 : 0;   // A uses lo-half on seg 2
        const int sb = (seg == 1) ? 256 : 0;   // B uses lo-half on seg 1
        const ushort_t* Ab = Zs + (size_t)m0 * 512 + sa;
        const ushort_t* Bb = Cs + (size_t)n0 * 512 + sb;
#pragma unroll 1
        for (int k0 = 0; k0 < 256; k0 += 32) {
            {
                int r0 = (wid * 2 + 0) * 16 + srow;
                int r1 = (wid * 2 + 1) * 16 + srow;
                gload16(Ab + (size_t)r0 * 512 + k0 + scol, As + (wid * 2 + 0) * 512);
                gload16(Ab + (size_t)r1 * 512 + k0 + scol, As + (wid * 2 + 1) * 512);
                gload16(Bb + (size_t)r0 * 512 + k0 + scol, Bs + (wid * 2 + 0) * 512);
                gload16(Bb + (size_t)r1 * 512 + k0 + scol, Bs + (wid * 2 + 1) * 512);
            }
            __syncthreads();
            const ushort_t* Aw = As + (wm * 64) * 32;
            const ushort_t* Bw = Bs + (wn * 64) * 32;
            short8v a[4], b[4];
#pragma unroll
            for (int mi = 0; mi < 4; ++mi)
                a[mi] = *(const short8v*)(Aw + (size_t)(mi * 16 + (lane & 15)) * 32 + (lane >> 4) * 8);
#pragma unroll
            for (int ni = 0; ni < 4; ++ni)
                b[ni] = *(const short8v*)(Bw + (size_t)(ni * 16 + (lane & 15)) * 32 + (lane >> 4) * 8);
#pragma unroll
            for (int mi = 0; mi < 4; ++mi)
#pragma unroll
                for (int ni = 0; ni < 4; ++ni)
                    acc[mi][ni] = __builtin_amdgcn_mfma_f32_16x16x32_bf16(
                        a[mi], b[ni], acc[mi][ni], 0, 0, 0);
            __syncthreads();
        }
    }

    // epilogue: per-row top-2 over this wave's 64 cols (FULLY unrolled)
    unsigned long long* cand = (unsigned long long*)As;  // [128][4] = 4 KiB
#pragma unroll
    for (int mi = 0; mi < 4; ++mi) {
#pragma unroll
        for (int r = 0; r < 4; ++r) {
            int lrow = wm * 64 + mi * 16 + (lane >> 4) * 4 + r;
            float ar = asum[m0 + lrow];
            unsigned long long b1 = 0xFFFFFFFFFFFFFFFFull, b2 = 0xFFFFFFFFFFFFFFFFull;
#pragma unroll
            for (int ni = 0; ni < 4; ++ni) {
                int lcol = wn * 64 + ni * 16 + (lane & 15);
                float bc = bsum[n0 + lcol];
                float dt = (ar + bc) - 2.0f * acc[mi][ni][r];
                unsigned long long p =
                    ((unsigned long long)__float_as_uint(dt) << 32) | (unsigned)(n0 + lcol);
                unsigned long long nb1 = umin64(b1, p);
                unsigned long long nb2 = umin64(b2, umax64(b1, p));
                b1 = nb1; b2 = nb2;
            }
#pragma unroll
            for (int s = 1; s < 16; s <<= 1) {
                unsigned long long o1 = shflxor64(b1, s);
                unsigned long long o2 = shflxor64(b2, s);
                unsigned long long n1 = umin64(b1, o1);
                unsigned long long n2 = umin64(umax64(b1, o1), umin64(b2, o2));
                b1 = n1; b2 = n2;
            }
            if ((lane & 15) == 0) {
                cand[(size_t)lrow * 4 + wn * 2 + 0] = b1;
                cand[(size_t)lrow * 4 + wn * 2 + 1] = b2;
            }
        }
    }
    __syncthreads();
    // coalesced write: blockcand[row][group=bn*2+wn][2]
    {
        int row = t >> 1, pair = t & 1;
        unsigned long long v0 = cand[(size_t)row * 4 + pair * 2 + 0];
        unsigned long long v1 = cand[(size_t)row * 4 + pair * 2 + 1];
        unsigned long long* dst =
            blockcand + (size_t)(m0 + row) * 256 + (size_t)bn * 4 + pair * 2;
        dst[0] = v0; dst[1] = v1;
    }
}

// ---------------------------------------------------------------------------
// Phase 2 + finalize: per row (one wave), threshold-scan 256 candidates,
// exact fp32 quantized distance per survivor (np-structured), index tiebreak,
// then z_q_st / min_idx / loss exactly as round-1.
// ---------------------------------------------------------------------------
__global__ __launch_bounds__(256) void phase2_kernel(
    const float* __restrict__ Z, const float* __restrict__ CB,
    const float* __restrict__ asum, const float* __restrict__ bsum,
    const unsigned long long* __restrict__ blockcand,
    float* __restrict__ out, float* __restrict__ loss_acc) {
    float* out_zq = out + 2;
    float* out_idx = out + 2 + (size_t)N_ELEM;
    const int lane = threadIdx.x & 63;
    const int w = threadIdx.x >> 6;
    const int row = blockIdx.x * 4 + w;
    float lsum = 0.0f;

    if (row < M_ROWS) {
        const unsigned long long* cr = blockcand + (size_t)row * 256;
        unsigned long long e0 = cr[lane], e1 = cr[lane + 64];
        unsigned long long e2 = cr[lane + 128], e3 = cr[lane + 192];
        unsigned long long mn = umin64(umin64(e0, e1), umin64(e2, e3));
#pragma unroll
        for (int s = 1; s < 64; s <<= 1) mn = umin64(mn, shflxor64(mn, s));
        float dmin = __uint_as_float((unsigned)(mn >> 32));
        float thr = dmin + 8.0e-5f;
        unsigned long long m0m = __ballot(__uint_as_float((unsigned)(e0 >> 32)) <= thr);
        unsigned long long m1m = __ballot(__uint_as_float((unsigned)(e1 >> 32)) <= thr);
        unsigned long long m2m = __ballot(__uint_as_float((unsigned)(e2 >> 32)) <= thr);
        unsigned long long m3m = __ballot(__uint_as_float((unsigned)(e3 >> 32)) <= thr);

        const float4 zv = *(const float4*)(Z + (size_t)row * D_DIM + lane * 4);
        float ar = asum[row];
        unsigned long long best = 0xFFFFFFFFFFFFFFFFull;

        while (m0m | m1m | m2m | m3m) {
            unsigned long long e;
            if (m0m)      { int b = __ffsll((unsigned long long)m0m) - 1; m0m &= m0m - 1; e = shfl64(e0, b); }
            else if (m1m) { int b = __ffsll((unsigned long long)m1m) - 1; m1m &= m1m - 1; e = shfl64(e1, b); }
            else if (m2m) { int b = __ffsll((unsigned long long)m2m) - 1; m2m &= m2m - 1; e = shfl64(e2, b); }
            else          { int b = __ffsll((unsigned long long)m3m) - 1; m3m &= m3m - 1; e = shfl64(e3, b); }
            unsigned col = (unsigned)e;
            const float4 cv = *(const float4*)(CB + (size_t)col * D_DIM + lane * 4);
            float s = __fmul_rn(zv.x, cv.x);
            s = __builtin_fmaf(zv.y, cv.y, s);
            s = __builtin_fmaf(zv.z, cv.z, s);
            s = __builtin_fmaf(zv.w, cv.w, s);
#pragma unroll
            for (int m = 1; m < 64; m <<= 1) s += __shfl_xor(s, m);
            float d = __fsub_rn(__fadd_rn(ar, bsum[col]), __fmul_rn(2.0f, s));
            unsigned long long p = ((unsigned long long)__float_as_uint(d) << 32) | col;
            best = umin64(best, p);
        }

        unsigned wincol = (unsigned)best;
        if (lane == 0) out_idx[row] = (float)wincol;
        const float4 cv = *(const float4*)(CB + (size_t)wincol * D_DIM + lane * 4);
        float d0 = __fsub_rn(cv.x, zv.x);
        float d1 = __fsub_rn(cv.y, zv.y);
        float d2 = __fsub_rn(cv.z, zv.z);
        float d3 = __fsub_rn(cv.w, zv.w);
        float2 o0 = make_float2(__fadd_rn(zv.x, d0), __fadd_rn(zv.y, d1));
        float2 o1 = make_float2(__fadd_rn(zv.z, d2), __fadd_rn(zv.w, d3));
        *(float2*)(out_zq + (size_t)row * D_DIM + lane * 4) = o0;
        *(float2*)(out_zq + (size_t)row * D_DIM + lane * 4 + 2) = o1;
        lsum = d0 * d0 + d1 * d1 + d2 * d2 + d3 * d3;
    }
#pragma unroll
    for (int m = 1; m < 64; m <<= 1) lsum += __shfl_xor(lsum, m);
    __shared__ float red[4];
    if (lane == 0) red[w] = lsum;
    __syncthreads();
    if (threadIdx.x == 0) {
        float s = ((red[0] + red[1]) + (red[2] + red[3]));
        atomicAdd(loss_acc, s);
    }
}

__global__ void write_losses(const float* __restrict__ loss_acc,
                             float* __restrict__ out) {
    float l = __fdiv_rn(loss_acc[0], (float)N_ELEM);
    out[0] = l;
    out[1] = l;
}

// ======================= round-1 fallback (fp32 VALU) =======================
#define BM 128
#define BN 128
#define BK 32
#define LDT 132

__global__ __launch_bounds__(256) void gemm_argmin_kernel(
    const float* __restrict__ Z, const float* __restrict__ CB,
    const float* __restrict__ asum, const float* __restrict__ bsum,
    unsigned long long* __restrict__ packed) {
    __shared__ float As[BK][LDT];
    __shared__ float Bs[BK][LDT];
    const int bid = blockIdx.x;
    const int bm = bid >> 6, bn = bid & 63;
    const int m0 = bm * BM, n0 = bn * BN;
    const int t = threadIdx.x;
    const int ty = t >> 4, tx = t & 15;
    float acc[8][8];
#pragma unroll
    for (int i = 0; i < 8; ++i)
#pragma unroll
        for (int j = 0; j < 8; ++j) acc[i][j] = 0.0f;
    for (int k0 = 0; k0 < D_DIM; k0 += BK) {
#pragma unroll
        for (int i = 0; i < 4; ++i) {
            int idx = t + i * 256;
            int row = idx >> 3, kq = idx & 7;
            const float4 av = *(const float4*)(Z + (size_t)(m0 + row) * D_DIM + k0 + kq * 4);
            As[kq * 4 + 0][row] = av.x; As[kq * 4 + 1][row] = av.y;
            As[kq * 4 + 2][row] = av.z; As[kq * 4 + 3][row] = av.w;
            const float4 bv = *(const float4*)(CB + (size_t)(n0 + row) * D_DIM + k0 + kq * 4);
            Bs[kq * 4 + 0][row] = bv.x; Bs[kq * 4 + 1][row] = bv.y;
            Bs[kq * 4 + 2][row] = bv.z; Bs[kq * 4 + 3][row] = bv.w;
        }
        __syncthreads();
#pragma unroll
        for (int k = 0; k < BK; ++k) {
            float af[8], bf[8];
            *(float4*)(af)     = *(const float4*)(&As[k][ty * 4]);
            *(float4*)(af + 4) = *(const float4*)(&As[k][64 + ty * 4]);
            *(float4*)(bf)     = *(const float4*)(&Bs[k][tx * 4]);
            *(float4*)(bf + 4) = *(const float4*)(&Bs[k][64 + tx * 4]);
#pragma unroll
            for (int i = 0; i < 8; ++i)
#pragma unroll
                for (int j = 0; j < 8; ++j)
                    acc[i][j] = __builtin_fmaf(af[i], bf[j], acc[i][j]);
        }
        __syncthreads();
    }
    float ar[8], bc[8];
    int rowIdx[8], colIdx[8];
#pragma unroll
    for (int i = 0; i < 8; ++i) {
        rowIdx[i] = (i < 4) ? (4 * ty + i) : (64 + 4 * ty + (i - 4));
        ar[i] = asum[m0 + rowIdx[i]];
    }
#pragma unroll
    for (int j = 0; j < 8; ++j) {
        colIdx[j] = (j < 4) ? (4 * tx + j) : (64 + 4 * tx + (j - 4));
        bc[j] = bsum[n0 + colIdx[j]];
    }
#pragma unroll
    for (int i = 0; i < 8; ++i) {
        unsigned long long best = 0xFFFFFFFFFFFFFFFFull;
#pragma unroll
        for (int j = 0; j < 8; ++j) {
            float ts = __fadd_rn(ar[i], bc[j]);
            float d = __fsub_rn(ts, __fmul_rn(2.0f, acc[i][j]));
            unsigned long long p = ((unsigned long long)__float_as_uint(d) << 32) |
                                   (unsigned)(n0 + colIdx[j]);
            best = (p < best) ? p : best;
        }
#pragma unroll
        for (int m = 1; m <= 8; m <<= 1) {
            unsigned long long o = shflxor64(best, m);
            best = (o < best) ? o : best;
        }
        if (tx == 0) atomicMin(&packed[m0 + rowIdx[i]], best);
    }
}

__global__ __launch_bounds__(256) void finalize_kernel(
    const float* __restrict__ Z, const float* __restrict__ CB,
    const unsigned long long* __restrict__ packed,
    float* __restrict__ out, float* __restrict__ loss_acc) {
    float* out_zq = out + 2;
    float* out_idx = out + 2 + (size_t)N_ELEM;
    const int lane = threadIdx.x & 63;
    const int wid = (blockIdx.x * blockDim.x + threadIdx.x) >> 6;
    const int nw = (gridDim.x * blockDim.x) >> 6;
    float lsum = 0.0f;
    for (int row = wid; row < M_ROWS; row += nw) {
        unsigned long long pk = packed[row];
        unsigned idx = (unsigned)(pk & 0xFFFFFFFFull);
        if (lane == 0) out_idx[row] = (float)idx;
        const float4 zv = *(const float4*)(Z + (size_t)row * D_DIM + lane * 4);
        const float4 cv = *(const float4*)(CB + (size_t)idx * D_DIM + lane * 4);
        float d0 = __fsub_rn(cv.x, zv.x);
        float d1 = __fsub_rn(cv.y, zv.y);
        float d2 = __fsub_rn(cv.z, zv.z);
        float d3 = __fsub_rn(cv.w, zv.w);
        float2 o0 = make_float2(__fadd_rn(zv.x, d0), __fadd_rn(zv.y, d1));
        float2 o1 = make_float2(__fadd_rn(zv.z, d2), __fadd_rn(zv.w, d3));
        *(float2*)(out_zq + (size_t)row * D_DIM + lane * 4) = o0;
        *(float2*)(out_zq + (size_t)row * D_DIM + lane * 4 + 2) = o1;
        lsum += d0 * d0 + d1 * d1 + d2 * d2 + d3 * d3;
    }
#pragma unroll
    for (int m = 1; m < 64; m <<= 1) lsum += __shfl_xor(lsum, m);
    __shared__ float red[4];
    if (lane == 0) red[threadIdx.x >> 6] = lsum;
    __syncthreads();
    if (threadIdx.x == 0) {
        float s = ((red[0] + red[1]) + (red[2] + red[3]));
        atomicAdd(loss_acc, s);
    }
}

// ===========================================================================
extern "C" void kernel_launch(void* const* d_in, const int* in_sizes, int n_in,
                              void* d_out, int out_size, void* d_ws, size_t ws_size,
                              hipStream_t stream) {
    const float* Z = (const float*)d_in[0];    // [17664, 256]
    const float* CB = (const float*)d_in[1];   // [8192, 256]
    float* out = (float*)d_out;
    char* ws = (char*)d_ws;

    const size_t offZs   = 0;
    const size_t offCs   = offZs + (size_t)M_ROWS * 512 * 2;
    const size_t offCand = offCs + (size_t)K_CODES * 512 * 2;
    const size_t offAsum = offCand + (size_t)M_ROWS * 256 * 8;
    const size_t offBsum = offAsum + (size_t)M_ROWS * 4;
    const size_t offLoss = offBsum + (size_t)K_CODES * 4;
    const size_t need    = offLoss + 64;

    if (ws_size >= need) {
        ushort_t* Zs = (ushort_t*)(ws + offZs);
        ushort_t* Cs = (ushort_t*)(ws + offCs);
        unsigned long long* blockcand = (unsigned long long*)(ws + offCand);
        float* asum = (float*)(ws + offAsum);
        float* bsum = (float*)(ws + offBsum);
        float* loss_acc = (float*)(ws + offLoss);

        hipLaunchKernelGGL(init_loss_kernel, dim3(1), dim3(64), 0, stream, loss_acc);
        hipLaunchKernelGGL(rowsq_kernel, dim3((M_ROWS + 255) / 256), dim3(256), 0, stream,
                           Z, asum, M_ROWS);
        hipLaunchKernelGGL(rowsq_kernel, dim3((K_CODES + 255) / 256), dim3(256), 0, stream,
                           CB, bsum, K_CODES);
        hipLaunchKernelGGL(split_kernel, dim3((M_ROWS * 64 + 255) / 256), dim3(256), 0, stream,
                           Z, Zs, M_ROWS);
        hipLaunchKernelGGL(split_kernel, dim3((K_CODES * 64 + 255) / 256), dim3(256), 0, stream,
                           CB, Cs, K_CODES);
        hipLaunchKernelGGL(phase1_kernel, dim3((M_ROWS / 128) * (K_CODES / 128)),
                           dim3(256), 0, stream, Zs, Cs, asum, bsum, blockcand);
        hipLaunchKernelGGL(phase2_kernel, dim3(M_ROWS / 4), dim3(256), 0, stream,
                           Z, CB, asum, bsum, blockcand, out, loss_acc);
        hipLaunchKernelGGL(write_losses, dim3(1), dim3(1), 0, stream, loss_acc, out);
    } else {
        float* asum = (float*)ws;
        float* bsum = (float*)(ws + (size_t)M_ROWS * 4);
        unsigned long long* packed =
            (unsigned long long*)(ws + (size_t)M_ROWS * 4 + (size_t)K_CODES * 4);
        float* loss_acc =
            (float*)(ws + (size_t)M_ROWS * 4 + (size_t)K_CODES * 4 + (size_t)M_ROWS * 8);

        hipLaunchKernelGGL(init_kernel, dim3((M_ROWS + 255) / 256), dim3(256), 0, stream,
                           packed, loss_acc);
        hipLaunchKernelGGL(rowsq_kernel, dim3((M_ROWS + 255) / 256), dim3(256), 0, stream,
                           Z, asum, M_ROWS);
        hipLaunchKernelGGL(rowsq_kernel, dim3((K_CODES + 255) / 256), dim3(256), 0, stream,
                           CB, bsum, K_CODES);
        hipLaunchKernelGGL(gemm_argmin_kernel, dim3((M_ROWS / BM) * (K_CODES / BN)),
                           dim3(256), 0, stream, Z, CB, asum, bsum, packed);
        hipLaunchKernelGGL(finalize_kernel, dim3(512), dim3(256), 0, stream,
                           Z, CB, packed, out, loss_acc);
        hipLaunchKernelGGL(write_losses, dim3(1), dim3(1), 0, stream, loss_acc, out);
    }
}